// Round 2
// baseline (573.249 us; speedup 1.0000x reference)
//
#include <hip/hip_runtime.h>

#define V 128000
#define NROWS 256
#define W 200
#define VW (V / 32)          // 4000 words of seen-bitmask
#define CAP 2048             // survivor capacity (top_k <= 1024 + ties)
#define TINYF 1.17549435e-38f

// ---- float <-> order-preserving uint key ----
__device__ __forceinline__ unsigned int fkey(float x) {
  unsigned int u = __float_as_uint(x);
  return (u & 0x80000000u) ? ~u : (u | 0x80000000u);
}
__device__ __forceinline__ float ikey(unsigned int k) {
  unsigned int u = (k & 0x80000000u) ? (k & 0x7FFFFFFFu) : ~k;
  return __uint_as_float(u);
}

// ---- jax threefry2x32, PARTITIONABLE layout (jax >= 0.4.30 default) ----
// counts = iota(uint64, S); counter = (hi32, lo32) = (0, t); key = (0, 42)
// 32-bit draw = bits1 ^ bits2 (lane XOR fold)
__device__ __forceinline__ unsigned int tf_bits(unsigned int t) {
  const unsigned int k0 = 0u, k1 = 42u;
  const unsigned int ks2 = k0 ^ k1 ^ 0x1BD11BDAu;
  unsigned int x0 = 0u + k0, x1 = t + k1;
  const unsigned int ksArr[3] = {k0, k1, ks2};
  const int RA[4] = {13, 15, 26, 6};
  const int RB[4] = {17, 29, 16, 24};
#pragma unroll
  for (int i = 0; i < 5; ++i) {
#pragma unroll
    for (int j = 0; j < 4; ++j) {
      int r = (i & 1) ? RB[j] : RA[j];
      x0 += x1;
      x1 = (x1 << r) | (x1 >> (32 - r));
      x1 ^= x0;
    }
    x0 += ksArr[(i + 1) % 3];
    x1 += ksArr[(i + 2) % 3] + (unsigned int)(i + 1);
  }
  return x0 ^ x1;
}

__global__ __launch_bounds__(1024) void sampler_kernel(
    const float* __restrict__ logits, const int* __restrict__ toks,
    const float* __restrict__ temps, const float* __restrict__ topps,
    const int* __restrict__ topks, const float* __restrict__ rps,
    float* __restrict__ out_ids, float* __restrict__ scratch) {
  __shared__ unsigned int s_seen[VW];   // 16000 B
  __shared__ int s_hist[4096];          // 16384 B
  __shared__ float s_sval[CAP];         // 8192 B
  __shared__ int s_sidx[CAP];           // 8192 B
  __shared__ float s_p[CAP];            // 8192 B
  __shared__ unsigned char s_keep[CAP]; // 2048 B
  __shared__ float s_redf[1024];
  __shared__ int s_redi[1024];
  __shared__ float s_m, s_kth, s_denom, s_denom2;
  __shared__ int s_b0, s_b1, s_need1, s_need2, s_cnt;

  const int row = blockIdx.x;
  const int tid = threadIdx.x;
  const int nt = blockDim.x;
  const float rp = rps[row];
  const float temp = temps[row];
  const float topp = topps[row];
  const int k = topks[row];
  const size_t base = (size_t)row * V;

  // ---- phase 0: seen bitmask + zero histogram ----
  for (int i = tid; i < VW; i += nt) s_seen[i] = 0u;
  for (int i = tid; i < 4096; i += nt) s_hist[i] = 0;
  __syncthreads();
  for (int i = tid; i < W; i += nt) {
    int tok = toks[row * W + i];
    if (tok >= 0 && tok < V) atomicOr(&s_seen[tok >> 5], 1u << (tok & 31));
  }
  __syncthreads();

  // ---- phase 1: penalty + temperature, store lg, max, level-0 histogram ----
  float lmax = -INFINITY;
  for (int q = tid; q < V / 4; q += nt) {
    float4 x4 = reinterpret_cast<const float4*>(logits + base)[q];
    float vals[4] = {x4.x, x4.y, x4.z, x4.w};
#pragma unroll
    for (int e = 0; e < 4; ++e) {
      int j = q * 4 + e;
      float x = vals[e];
      if ((s_seen[j >> 5] >> (j & 31)) & 1u) x = (x > 0.0f) ? x / rp : x * rp;
      x = x / temp;
      vals[e] = x;
      lmax = fmaxf(lmax, x);
      atomicAdd(&s_hist[fkey(x) >> 20], 1);
    }
    float4 o;
    o.x = vals[0]; o.y = vals[1]; o.z = vals[2]; o.w = vals[3];
    reinterpret_cast<float4*>(scratch + base)[q] = o;
  }
  s_redf[tid] = lmax;
  __syncthreads();
  for (int s = nt >> 1; s > 0; s >>= 1) {
    if (tid < s) s_redf[tid] = fmaxf(s_redf[tid], s_redf[tid + s]);
    __syncthreads();
  }
  if (tid == 0) {
    s_m = s_redf[0];
    int cum = 0, b = 4095;
    for (; b >= 0; --b) { cum += s_hist[b]; if (cum >= k) break; }
    s_b0 = b;
    s_need1 = k - (cum - s_hist[b]);
  }
  __syncthreads();
  const int b0 = s_b0;
  const int need1 = s_need1;

  // ---- phase 2: level-1 histogram (next 12 bits) ----
  for (int i = tid; i < 4096; i += nt) s_hist[i] = 0;
  __syncthreads();
  for (int j = tid; j < V; j += nt) {
    unsigned int mk = fkey(scratch[base + j]);
    if ((int)(mk >> 20) == b0) atomicAdd(&s_hist[(mk >> 8) & 0xFFFu], 1);
  }
  __syncthreads();
  if (tid == 0) {
    int cum = 0, b = 4095;
    for (; b >= 0; --b) { cum += s_hist[b]; if (cum >= need1) break; }
    s_b1 = b;
    s_need2 = need1 - (cum - s_hist[b]);
  }
  __syncthreads();
  const int b1 = s_b1;
  const int need2 = s_need2;
  const unsigned int pre24 = ((unsigned int)b0 << 12) | (unsigned int)b1;

  // ---- phase 3: level-2 histogram (last 8 bits) -> exact kth value ----
  for (int i = tid; i < 256; i += nt) s_hist[i] = 0;
  __syncthreads();
  for (int j = tid; j < V; j += nt) {
    unsigned int mk = fkey(scratch[base + j]);
    if ((mk >> 8) == pre24) atomicAdd(&s_hist[mk & 0xFFu], 1);
  }
  __syncthreads();
  if (tid == 0) {
    int cum = 0, b = 255;
    for (; b >= 0; --b) { cum += s_hist[b]; if (cum >= need2) break; }
    s_kth = ikey((pre24 << 8) | (unsigned int)b);
    s_cnt = 0;
  }
  __syncthreads();
  const float kth = s_kth;
  const float m = s_m;

  // ---- phase 4: gather survivors (x >= kth) ----
  for (int j = tid; j < V; j += nt) {
    float x = scratch[base + j];
    if (x >= kth) {
      int pos = atomicAdd(&s_cnt, 1);
      if (pos < CAP) { s_sval[pos] = x; s_sidx[pos] = j; }
    }
  }
  __syncthreads();
  const int S = min(s_cnt, CAP);
  for (int i = S + tid; i < CAP; i += nt) {
    s_sval[i] = INFINITY;
    s_sidx[i] = 0x7FFFFFFF;
  }
  __syncthreads();

  // ---- phase 5: bitonic sort ascending by (value, index) — jax stable sort ----
  for (int size = 2; size <= CAP; size <<= 1) {
    for (int stride = size >> 1; stride > 0; stride >>= 1) {
      for (int t = tid; t < CAP / 2; t += nt) {
        int pos = 2 * t - (t & (stride - 1));
        int q = pos + stride;
        bool up = ((pos & size) == 0);
        float v1 = s_sval[pos], v2 = s_sval[q];
        int i1 = s_sidx[pos], i2 = s_sidx[q];
        bool gt = (v1 > v2) || (v1 == v2 && i1 > i2);
        if (gt == up) {
          s_sval[pos] = v2; s_sval[q] = v1;
          s_sidx[pos] = i2; s_sidx[q] = i1;
        }
      }
      __syncthreads();
    }
  }

  // ---- phase 6: softmax denom over survivors ----
  float lsum = 0.0f;
  for (int i = tid; i < S; i += nt) lsum += expf(s_sval[i] - m);
  s_redf[tid] = lsum;
  __syncthreads();
  for (int s = nt >> 1; s > 0; s >>= 1) {
    if (tid < s) s_redf[tid] += s_redf[tid + s];
    __syncthreads();
  }
  if (tid == 0) s_denom = s_redf[0];
  __syncthreads();
  const float denom = s_denom;
  for (int i = tid; i < S; i += nt) s_p[i] = expf(s_sval[i] - m) / denom;
  __syncthreads();

  // ---- phase 7: sequential fp32 cumsum + top-p mask (last always kept) ----
  if (tid == 0) {
    float cs = 0.0f;
    float cut = 1.0f - topp;
    for (int i = 0; i < S; ++i) {
      cs += s_p[i];
      s_keep[i] = (cs <= cut) ? 0 : 1;
    }
    s_keep[S - 1] = 1;
  }
  __syncthreads();

  // ---- phase 8: final softmax denom over kept survivors ----
  lsum = 0.0f;
  for (int i = tid; i < S; i += nt)
    if (s_keep[i]) lsum += expf(s_sval[i] - m);
  s_redf[tid] = lsum;
  __syncthreads();
  for (int s = nt >> 1; s > 0; s >>= 1) {
    if (tid < s) s_redf[tid] += s_redf[tid + s];
    __syncthreads();
  }
  if (tid == 0) s_denom2 = s_redf[0];
  __syncthreads();
  const float denom2 = s_denom2;

  // ---- phase 9: write probs in place + Gumbel argmax over kept survivors ----
  float bs = -INFINITY;
  int bi = 0x7FFFFFFF;
  for (int j = tid; j < V; j += nt) {
    float x = scratch[base + j];
    float pr = 0.0f;
    if (x >= kth) {
      int lo = 0, hi = S;
      while (lo < hi) {
        int mid = (lo + hi) >> 1;
        float v = s_sval[mid];
        int id = s_sidx[mid];
        if (v < x || (v == x && id < j)) lo = mid + 1; else hi = mid;
      }
      if (s_keep[lo]) {
        pr = expf(x - m) / denom2;
        unsigned int t = (unsigned int)(row * V) + (unsigned int)j;
        unsigned int bbits = tf_bits(t);
        float u = __uint_as_float((bbits >> 9) | 0x3f800000u) - 1.0f;
        if (u < TINYF) u = TINYF;                 // jax: max(tiny, u)
        float g = -logf(-logf(u));
        float sc = x + g;
        if (sc > bs || (sc == bs && j < bi)) { bs = sc; bi = j; }
      }
    }
    scratch[base + j] = pr;
  }
  s_redf[tid] = bs;
  s_redi[tid] = bi;
  __syncthreads();
  for (int s = nt >> 1; s > 0; s >>= 1) {
    if (tid < s) {
      float ov = s_redf[tid + s];
      int oi = s_redi[tid + s];
      if (ov > s_redf[tid] || (ov == s_redf[tid] && oi < s_redi[tid])) {
        s_redf[tid] = ov;
        s_redi[tid] = oi;
      }
    }
    __syncthreads();
  }
  if (tid == 0) out_ids[row] = (float)s_redi[0];
}

extern "C" void kernel_launch(void* const* d_in, const int* in_sizes, int n_in,
                              void* d_out, int out_size, void* d_ws, size_t ws_size,
                              hipStream_t stream) {
  (void)in_sizes; (void)d_ws; (void)ws_size; (void)out_size;
  if (n_in < 6) return;
  const float* logits = (const float*)d_in[0];
  const int* toks = (const int*)d_in[1];
  const float* temps = (const float*)d_in[2];
  const float* topps = (const float*)d_in[3];
  const int* topks = (const int*)d_in[4];
  const float* rps = (const float*)d_in[5];
  float* out = (float*)d_out;            // [0,256): ids as float; [256,...): probs
  float* scratch = out + NROWS;          // probs region doubles as lg scratch
  sampler_kernel<<<dim3(NROWS), dim3(1024), 0, stream>>>(
      logits, toks, temps, topps, topks, rps, out, scratch);
}

// Round 4
// 220.773 us; speedup vs baseline: 2.5966x; 2.5966x over previous
//
#include <hip/hip_runtime.h>

#define V 128000
#define V4 (V / 4)
#define NCHUNK (V / 16)      // 8000 chunk-max entries (16 elems each)
#define NROWS 256
#define W 200
#define VW (V / 32)          // 4000 words of seen-bitmask
#define CAP 4096             // gathered-candidate capacity (k<=1024 + bucket slack)
#define TINYF 1.17549435e-38f
#define NT 1024
#define NWAVE 16

typedef float vfloat4 __attribute__((ext_vector_type(4)));

// ---- float <-> order-preserving uint key ----
__device__ __forceinline__ unsigned int fkey(float x) {
  unsigned int u = __float_as_uint(x);
  return (u & 0x80000000u) ? ~u : (u | 0x80000000u);
}

// ---- jax threefry2x32, partitionable layout: counter=(0,t), key=(0,42), fold=xor ----
__device__ __forceinline__ unsigned int tf_bits(unsigned int t) {
  const unsigned int k0 = 0u, k1 = 42u;
  const unsigned int ks2 = k0 ^ k1 ^ 0x1BD11BDAu;
  unsigned int x0 = 0u + k0, x1 = t + k1;
  const unsigned int ksArr[3] = {k0, k1, ks2};
  const int RA[4] = {13, 15, 26, 6};
  const int RB[4] = {17, 29, 16, 24};
#pragma unroll
  for (int i = 0; i < 5; ++i) {
#pragma unroll
    for (int j = 0; j < 4; ++j) {
      int r = (i & 1) ? RB[j] : RA[j];
      x0 += x1;
      x1 = (x1 << r) | (x1 >> (32 - r));
      x1 ^= x0;
    }
    x0 += ksArr[(i + 1) % 3];
    x1 += ksArr[(i + 2) % 3] + (unsigned int)(i + 1);
  }
  return x0 ^ x1;
}

__global__ __launch_bounds__(1024, 1) void sampler_kernel(
    const float* __restrict__ logits, const int* __restrict__ toks,
    const float* __restrict__ temps, const float* __restrict__ topps,
    const int* __restrict__ topks, const float* __restrict__ rps,
    float* __restrict__ out_ids, float* __restrict__ probs) {
  __shared__ unsigned int s_seen[VW];    // 16000 B
  __shared__ int s_hist[4096];           // 16384 B
  __shared__ unsigned int s_cmax[NCHUNK];// 32000 B  per-16-elem max fkey
  __shared__ float s_sval[CAP];          // 16384 B
  __shared__ int s_sidx[CAP];            // 16384 B
  __shared__ float s_e[CAP];             // 16384 B  exp terms, later probs
  __shared__ unsigned char s_keep[CAP];  // 4096 B
  __shared__ int s_csum[64];
  __shared__ float s_wredf[NWAVE];
  __shared__ int s_wredi[NWAVE];
  __shared__ float s_m, s_denom, s_denom2;
  __shared__ int s_b0, s_cnt, s_p0;

  const int row = blockIdx.x;
  const int tid = threadIdx.x;
  const int lane = tid & 63;
  const int wid = tid >> 6;
  const float rp = rps[row];
  const float temp = temps[row];
  const float topp = topps[row];
  const int k = topks[row];
  const size_t base = (size_t)row * V;
  const float4* __restrict__ lg4 = reinterpret_cast<const float4*>(logits + base);
  vfloat4* __restrict__ pr4 = reinterpret_cast<vfloat4*>(probs + base);

  // ---- phase 0: seen bitmask + zero histogram ----
  for (int i = tid; i < VW; i += NT) s_seen[i] = 0u;
  for (int i = tid; i < 4096; i += NT) s_hist[i] = 0;
  __syncthreads();
  for (int i = tid; i < W; i += NT) {
    int tok = toks[row * W + i];
    if (tok >= 0 && tok < V) atomicOr(&s_seen[tok >> 5], 1u << (tok & 31));
  }
  __syncthreads();

  // ---- pass 1: transform, max, 4096-bucket histogram, chunk-max ----
  float lmax = -INFINITY;
  for (int q = tid; q < V4; q += NT) {
    float4 x4 = lg4[q];
    float xs[4] = {x4.x, x4.y, x4.z, x4.w};
    const int j0 = q * 4;
    const int sh = j0 & 31;
    unsigned long long ww = (unsigned long long)s_seen[j0 >> 5] |
                            ((unsigned long long)s_seen[(j0 + 3) >> 5] << 32);
    unsigned int kmax = 0u;
#pragma unroll
    for (int e = 0; e < 4; ++e) {
      float x = xs[e];
      if ((ww >> (sh + e)) & 1ull) x = (x > 0.0f) ? x / rp : x * rp;
      x = x / temp;
      xs[e] = x;
      lmax = fmaxf(lmax, x);
      unsigned int ky = fkey(x);
      kmax = kmax > ky ? kmax : ky;
      atomicAdd(&s_hist[ky >> 20], 1);
    }
    unsigned int r1 = kmax, o;
    o = __shfl_xor(r1, 1); r1 = r1 > o ? r1 : o;
    o = __shfl_xor(r1, 2); r1 = r1 > o ? r1 : o;
    if ((lane & 3) == 0) s_cmax[q >> 2] = r1;
  }
#pragma unroll
  for (int d = 32; d > 0; d >>= 1) lmax = fmaxf(lmax, __shfl_xor(lmax, d));
  if (lane == 0) s_wredf[wid] = lmax;
  __syncthreads();

  // ---- select bucket b0 (parallel chunk sums + short serial scan) ----
  if (tid < 64) {
    int sm = 0;
    const int b = tid * 64;
    for (int i = 0; i < 64; ++i) sm += s_hist[b + i];
    s_csum[tid] = sm;
  }
  __syncthreads();
  if (tid == 0) {
    float mm = s_wredf[0];
    for (int i = 1; i < NWAVE; ++i) mm = fmaxf(mm, s_wredf[i]);
    s_m = mm;
    int cumAbove = 0, c = 63;
    for (; c > 0; --c) {
      if (cumAbove + s_csum[c] >= k) break;
      cumAbove += s_csum[c];
    }
    int cum = cumAbove, b0v = c * 64;
    for (int b = c * 64 + 63; b >= c * 64; --b) {
      cum += s_hist[b];
      if (cum >= k) { b0v = b; break; }
    }
    s_b0 = b0v;
    s_cnt = 0;
  }
  __syncthreads();

  // ---- pass 2: gather all elements in buckets >= b0 (chunk-max filtered) ----
  const unsigned int fk0 = ((unsigned int)s_b0) << 20;
  for (int q = tid; q < V4; q += NT) {
    if (s_cmax[q >> 2] < fk0) continue;
    float4 x4 = lg4[q];
    float xs[4] = {x4.x, x4.y, x4.z, x4.w};
    const int j0 = q * 4;
    const int sh = j0 & 31;
    unsigned long long ww = (unsigned long long)s_seen[j0 >> 5] |
                            ((unsigned long long)s_seen[(j0 + 3) >> 5] << 32);
#pragma unroll
    for (int e = 0; e < 4; ++e) {
      float x = xs[e];
      if ((ww >> (sh + e)) & 1ull) x = (x > 0.0f) ? x / rp : x * rp;
      x = x / temp;
      if (fkey(x) >= fk0) {
        int pos = atomicAdd(&s_cnt, 1);
        if (pos < CAP) { s_sval[pos] = x; s_sidx[pos] = j0 + e; }
      }
    }
  }
  __syncthreads();
  int G = s_cnt;
  if (G > CAP) G = CAP;

  // ---- bitonic sort G candidates ascending by (value, index) ----
  int np2 = 2;
  while (np2 < G) np2 <<= 1;
  for (int i = G + tid; i < np2; i += NT) {
    s_sval[i] = INFINITY;
    s_sidx[i] = 0x7FFFFFFF;
  }
  __syncthreads();
  for (int size = 2; size <= np2; size <<= 1) {
    for (int stride = size >> 1; stride > 0; stride >>= 1) {
      for (int t2 = tid; t2 < (np2 >> 1); t2 += NT) {
        int pos = 2 * t2 - (t2 & (stride - 1));
        int qq = pos + stride;
        bool up = ((pos & size) == 0);
        float v1 = s_sval[pos], v2 = s_sval[qq];
        int i1 = s_sidx[pos], i2 = s_sidx[qq];
        bool gt = (v1 > v2) || (v1 == v2 && i1 > i2);
        if (gt == up) {
          s_sval[pos] = v2; s_sval[qq] = v1;
          s_sidx[pos] = i2; s_sidx[qq] = i1;
        }
      }
      __syncthreads();
    }
  }

  // ---- exact kth value + survivor range [p0, G) ----
  int kk = k > G ? G : k;
  const float kth = s_sval[G - kk];
  const float m = s_m;
  for (int i = tid; i < G; i += NT) {
    if (s_sval[i] >= kth && (i == 0 || s_sval[i - 1] < kth)) s_p0 = i;
  }
  __syncthreads();
  const int p0 = s_p0;

  // ---- softmax denom over survivors ----
  float part = 0.0f;
  for (int i = p0 + tid; i < G; i += NT) {
    float e = expf(s_sval[i] - m);
    s_e[i] = e;
    part += e;
  }
#pragma unroll
  for (int d = 32; d > 0; d >>= 1) part += __shfl_xor(part, d);
  if (lane == 0) s_wredf[wid] = part;
  __syncthreads();
  if (tid == 0) {
    float s = 0.0f;
    for (int i = 0; i < NWAVE; ++i) s += s_wredf[i];
    s_denom = s;
  }
  __syncthreads();
  const float denom = s_denom;

  // ---- sequential fp32 cumsum + top-p mask (batched loads, last kept) ----
  if (tid == 0) {
    const float cut = 1.0f - topp;
    float cs = 0.0f;
    int i = p0;
    for (; i + 8 <= G; i += 8) {
      float v0 = s_e[i], v1 = s_e[i + 1], v2 = s_e[i + 2], v3 = s_e[i + 3];
      float v4 = s_e[i + 4], v5 = s_e[i + 5], v6 = s_e[i + 6], v7 = s_e[i + 7];
      float d0 = v0 / denom, d1 = v1 / denom, d2 = v2 / denom, d3 = v3 / denom;
      float d4 = v4 / denom, d5 = v5 / denom, d6 = v6 / denom, d7 = v7 / denom;
      cs += d0; s_keep[i] = (cs <= cut) ? 0 : 1;
      cs += d1; s_keep[i + 1] = (cs <= cut) ? 0 : 1;
      cs += d2; s_keep[i + 2] = (cs <= cut) ? 0 : 1;
      cs += d3; s_keep[i + 3] = (cs <= cut) ? 0 : 1;
      cs += d4; s_keep[i + 4] = (cs <= cut) ? 0 : 1;
      cs += d5; s_keep[i + 5] = (cs <= cut) ? 0 : 1;
      cs += d6; s_keep[i + 6] = (cs <= cut) ? 0 : 1;
      cs += d7; s_keep[i + 7] = (cs <= cut) ? 0 : 1;
    }
    for (; i < G; ++i) {
      cs += s_e[i] / denom;
      s_keep[i] = (cs <= cut) ? 0 : 1;
    }
    s_keep[G - 1] = 1;
  }
  __syncthreads();

  // ---- final denom over kept ----
  part = 0.0f;
  for (int i = p0 + tid; i < G; i += NT)
    if (s_keep[i]) part += s_e[i];
#pragma unroll
  for (int d = 32; d > 0; d >>= 1) part += __shfl_xor(part, d);
  if (lane == 0) s_wredf[wid] = part;
  __syncthreads();
  if (tid == 0) {
    float s = 0.0f;
    for (int i = 0; i < NWAVE; ++i) s += s_wredf[i];
    s_denom2 = s;
  }
  __syncthreads();
  const float denom2 = s_denom2;

  // ---- overwrite s_e with final probs (0 for masked) ----
  for (int i = p0 + tid; i < G; i += NT)
    s_e[i] = s_keep[i] ? (s_e[i] / denom2) : 0.0f;
  __syncthreads();

  // ---- Gumbel scan over kept survivors (all in LDS) ----
  float bs = -INFINITY;
  int bi = 0x7FFFFFFF;
  for (int i = p0 + tid; i < G; i += NT) {
    if (!s_keep[i]) continue;
    int j = s_sidx[i];
    unsigned int t = (unsigned int)(row * V) + (unsigned int)j;
    unsigned int bb = tf_bits(t);
    float u = __uint_as_float((bb >> 9) | 0x3f800000u) - 1.0f;
    if (u < TINYF) u = TINYF;
    float g = -logf(-logf(u));
    float sc = s_sval[i] + g;
    if (sc > bs || (sc == bs && j < bi)) { bs = sc; bi = j; }
  }

  // ---- pass 3: write probs (chunk-max filtered; zeros without loads) ----
  const unsigned int kkey = fkey(kth);
  for (int q = tid; q < V4; q += NT) {
    vfloat4 o = (vfloat4){0.0f, 0.0f, 0.0f, 0.0f};
    if (s_cmax[q >> 2] >= kkey) {
      float4 x4 = lg4[q];
      float xs[4] = {x4.x, x4.y, x4.z, x4.w};
      float os[4];
      const int j0 = q * 4;
      const int sh = j0 & 31;
      unsigned long long ww = (unsigned long long)s_seen[j0 >> 5] |
                              ((unsigned long long)s_seen[(j0 + 3) >> 5] << 32);
#pragma unroll
      for (int e = 0; e < 4; ++e) {
        float x = xs[e];
        if ((ww >> (sh + e)) & 1ull) x = (x > 0.0f) ? x / rp : x * rp;
        x = x / temp;
        float pr = 0.0f;
        if (x >= kth) {
          int j = j0 + e;
          int lo = p0, hi = G;
          while (lo < hi) {
            int mid = (lo + hi) >> 1;
            float v = s_sval[mid];
            int id = s_sidx[mid];
            if (v < x || (v == x && id < j)) lo = mid + 1; else hi = mid;
          }
          pr = s_e[lo];
        }
        os[e] = pr;
      }
      o.x = os[0]; o.y = os[1]; o.z = os[2]; o.w = os[3];
    }
    __builtin_nontemporal_store(o, &pr4[q]);
  }

  // ---- argmax reduce -> sampled id ----
#pragma unroll
  for (int d = 32; d > 0; d >>= 1) {
    float ov = __shfl_down(bs, d);
    int oi = __shfl_down(bi, d);
    if (ov > bs || (ov == bs && oi < bi)) { bs = ov; bi = oi; }
  }
  if (lane == 0) { s_wredf[wid] = bs; s_wredi[wid] = bi; }
  __syncthreads();
  if (tid == 0) {
    float bb = s_wredf[0];
    int bj = s_wredi[0];
    for (int i = 1; i < NWAVE; ++i) {
      if (s_wredf[i] > bb || (s_wredf[i] == bb && s_wredi[i] < bj)) {
        bb = s_wredf[i];
        bj = s_wredi[i];
      }
    }
    out_ids[row] = (float)bj;
  }
}

extern "C" void kernel_launch(void* const* d_in, const int* in_sizes, int n_in,
                              void* d_out, int out_size, void* d_ws, size_t ws_size,
                              hipStream_t stream) {
  (void)in_sizes; (void)d_ws; (void)ws_size; (void)out_size;
  if (n_in < 6) return;
  const float* logits = (const float*)d_in[0];
  const int* toks = (const int*)d_in[1];
  const float* temps = (const float*)d_in[2];
  const float* topps = (const float*)d_in[3];
  const int* topks = (const int*)d_in[4];
  const float* rps = (const float*)d_in[5];
  float* out = (float*)d_out;            // [0,256): ids as float; [256,...): probs
  float* probs = out + NROWS;
  sampler_kernel<<<dim3(NROWS), dim3(NT), 0, stream>>>(
      logits, toks, temps, topps, topks, rps, out, probs);
}

// Round 5
// 211.023 us; speedup vs baseline: 2.7165x; 1.0462x over previous
//
#include <hip/hip_runtime.h>

#define V 128000
#define V4 (V / 4)
#define NCHUNK (V / 16)      // 8000 chunk-max entries (16 elems each)
#define NROWS 256
#define W 200
#define VW (V / 32)          // 4000 words of seen-bitmask
#define CAP 8192             // gathered-candidate capacity
#define TINYF 1.17549435e-38f
#define NT 1024
#define NWAVE 16

typedef float vfloat4 __attribute__((ext_vector_type(4)));

// ---- float <-> order-preserving uint key ----
__device__ __forceinline__ unsigned int fkey(float x) {
  unsigned int u = __float_as_uint(x);
  return (u & 0x80000000u) ? ~u : (u | 0x80000000u);
}

// ---- jax threefry2x32, partitionable layout: counter=(0,t), key=(0,42), fold=xor ----
__device__ __forceinline__ unsigned int tf_bits(unsigned int t) {
  const unsigned int k0 = 0u, k1 = 42u;
  const unsigned int ks2 = k0 ^ k1 ^ 0x1BD11BDAu;
  unsigned int x0 = 0u + k0, x1 = t + k1;
  const unsigned int ksArr[3] = {k0, k1, ks2};
  const int RA[4] = {13, 15, 26, 6};
  const int RB[4] = {17, 29, 16, 24};
#pragma unroll
  for (int i = 0; i < 5; ++i) {
#pragma unroll
    for (int j = 0; j < 4; ++j) {
      int r = (i & 1) ? RB[j] : RA[j];
      x0 += x1;
      x1 = (x1 << r) | (x1 >> (32 - r));
      x1 ^= x0;
    }
    x0 += ksArr[(i + 1) % 3];
    x1 += ksArr[(i + 2) % 3] + (unsigned int)(i + 1);
  }
  return x0 ^ x1;
}

__device__ __forceinline__ float xform(float x, bool seen, float rp, float irp,
                                        float itemp) {
  if (seen) x = (x > 0.0f) ? x * irp : x * rp;
  return x * itemp;
}

__global__ __launch_bounds__(1024, 1) void sampler_kernel(
    const float* __restrict__ logits, const int* __restrict__ toks,
    const float* __restrict__ temps, const float* __restrict__ topps,
    const int* __restrict__ topks, const float* __restrict__ rps,
    float* __restrict__ out_ids, float* __restrict__ probs) {
  __shared__ unsigned int s_seen[VW];        // 16000 B
  __shared__ int s_hist[4096];               // 16384 B
  __shared__ unsigned short s_cmax16[NCHUNK];// 16000 B  per-16-elem max fkey>>16
  __shared__ float s_sval[CAP];              // 32768 B
  __shared__ int s_sidx[CAP];                // 32768 B
  __shared__ float s_e[CAP];                 // 32768 B  exp terms, later probs
  __shared__ unsigned char s_keep[CAP];      // 8192 B
  __shared__ float s_wredf[NWAVE];
  __shared__ int s_wredi[NWAVE];
  __shared__ float s_m, s_denom, s_denom2;
  __shared__ int s_b0, s_cnt, s_p0;

  const int row = blockIdx.x;
  const int tid = threadIdx.x;
  const int lane = tid & 63;
  const int wid = tid >> 6;
  const float rp = rps[row];
  const float irp = 1.0f / rp;
  const float itemp = 1.0f / temps[row];
  const float topp = topps[row];
  const int k = topks[row];
  const size_t base = (size_t)row * V;
  const float4* __restrict__ lg4 = reinterpret_cast<const float4*>(logits + base);
  vfloat4* __restrict__ pr4 = reinterpret_cast<vfloat4*>(probs + base);

  // ---- phase 0: seen bitmask ----
  for (int i = tid; i < VW; i += NT) s_seen[i] = 0u;
  for (int i = tid; i < 4096; i += NT) s_hist[i] = 0;
  __syncthreads();
  for (int i = tid; i < W; i += NT) {
    int tok = toks[row * W + i];
    if (tok >= 0 && tok < V) atomicOr(&s_seen[tok >> 5], 1u << (tok & 31));
  }
  __syncthreads();

  // ---- pass 1: transform, max, chunk-max (NO element atomics) ----
  float lmax = -INFINITY;
  for (int qb = 0; qb < V4; qb += NT) {
    const int q = qb + tid;
    unsigned int kmax = 0u;
    if (q < V4) {
      float4 x4 = lg4[q];
      float xs[4] = {x4.x, x4.y, x4.z, x4.w};
      const int j0 = q * 4;
      const int sh = j0 & 31;
      unsigned long long ww = (unsigned long long)s_seen[j0 >> 5] |
                              ((unsigned long long)s_seen[(j0 + 3) >> 5] << 32);
#pragma unroll
      for (int e = 0; e < 4; ++e) {
        float x = xform(xs[e], (ww >> (sh + e)) & 1ull, rp, irp, itemp);
        lmax = fmaxf(lmax, x);
        unsigned int ky = fkey(x);
        kmax = kmax > ky ? kmax : ky;
      }
    }
    unsigned int o;
    o = __shfl_xor(kmax, 1); kmax = kmax > o ? kmax : o;
    o = __shfl_xor(kmax, 2); kmax = kmax > o ? kmax : o;
    if (((lane & 3) == 0) && (q < V4)) s_cmax16[q >> 2] = (unsigned short)(kmax >> 16);
  }
#pragma unroll
  for (int d = 32; d > 0; d >>= 1) lmax = fmaxf(lmax, __shfl_xor(lmax, d));
  if (lane == 0) s_wredf[wid] = lmax;
  __syncthreads();

  // ---- chunk-max histogram (8000 atomics vs 128000) ----
  for (int i = tid; i < NCHUNK; i += NT)
    atomicAdd(&s_hist[s_cmax16[i] >> 4], 1);
  __syncthreads();

  // ---- bucket select, wave-parallel (wave 0); wave 1 computes m ----
  if (wid == 1 && lane == 0) {
    float mm = s_wredf[0];
    for (int i = 1; i < NWAVE; ++i) mm = fmaxf(mm, s_wredf[i]);
    s_m = mm;
  }
  if (wid == 0) {
    int sm = 0;
    const int bb = lane * 64;
    for (int i = 0; i < 64; ++i) sm += s_hist[bb + i];
    int sfx = sm;
#pragma unroll
    for (int d = 1; d < 64; d <<= 1) {
      int t = __shfl_down(sfx, d);
      if (lane + d < 64) sfx += t;
    }
    unsigned long long mk = __ballot(sfx >= k);
    const int cstar = 63 - __builtin_clzll(mk);
    const int above = __shfl(sfx, cstar) - __shfl(sm, cstar);  // count above chunk cstar
    int h = s_hist[cstar * 64 + lane];
    int sfx2 = h;
#pragma unroll
    for (int d = 1; d < 64; d <<= 1) {
      int t = __shfl_down(sfx2, d);
      if (lane + d < 64) sfx2 += t;
    }
    unsigned long long mk2 = __ballot(above + sfx2 >= k);
    const int boff = 63 - __builtin_clzll(mk2);
    if (lane == 0) { s_b0 = cstar * 64 + boff; s_cnt = 0; }
  }
  __syncthreads();
  const int b0 = s_b0;

  // ---- pass 2: gather elements with fkey >= b0<<20 (chunk filter + wave-agg push) ----
  const unsigned int fk0 = ((unsigned int)b0) << 20;
  const int c16 = b0 << 4;
  for (int qb = 0; qb < V4; qb += NT) {
    const int q = qb + tid;
    const bool act = (q < V4) && ((int)s_cmax16[q >> 2] >= c16);
    float xs[4];
    bool pr[4] = {false, false, false, false};
    const int j0 = q * 4;
    if (act) {
      float4 x4 = lg4[q];
      float raw[4] = {x4.x, x4.y, x4.z, x4.w};
      const int sh = j0 & 31;
      unsigned long long ww = (unsigned long long)s_seen[j0 >> 5] |
                              ((unsigned long long)s_seen[(j0 + 3) >> 5] << 32);
#pragma unroll
      for (int e = 0; e < 4; ++e) {
        xs[e] = xform(raw[e], (ww >> (sh + e)) & 1ull, rp, irp, itemp);
        pr[e] = (fkey(xs[e]) >= fk0);
      }
    }
#pragma unroll
    for (int e = 0; e < 4; ++e) {
      unsigned long long mask = __ballot(pr[e]);
      if (!mask) continue;
      int basep = 0;
      if (lane == 0) basep = atomicAdd(&s_cnt, __popcll(mask));
      basep = __shfl(basep, 0);
      if (pr[e]) {
        int pos = basep + __popcll(mask & ((1ull << lane) - 1ull));
        if (pos < CAP) { s_sval[pos] = xs[e]; s_sidx[pos] = j0 + e; }
      }
    }
  }
  __syncthreads();
  int G = s_cnt;
  if (G > CAP) G = CAP;

  // ---- bitonic sort G candidates ascending by (value, index) ----
  int np2 = 2;
  while (np2 < G) np2 <<= 1;
  for (int i = G + tid; i < np2; i += NT) {
    s_sval[i] = INFINITY;
    s_sidx[i] = 0x7FFFFFFF;
  }
  __syncthreads();
  for (int size = 2; size <= np2; size <<= 1) {
    for (int stride = size >> 1; stride > 0; stride >>= 1) {
      for (int t2 = tid; t2 < (np2 >> 1); t2 += NT) {
        int pos = 2 * t2 - (t2 & (stride - 1));
        int qq = pos + stride;
        bool up = ((pos & size) == 0);
        float v1 = s_sval[pos], v2 = s_sval[qq];
        int i1 = s_sidx[pos], i2 = s_sidx[qq];
        bool gt = (v1 > v2) || (v1 == v2 && i1 > i2);
        if (gt == up) {
          s_sval[pos] = v2; s_sval[qq] = v1;
          s_sidx[pos] = i2; s_sidx[qq] = i1;
        }
      }
      __syncthreads();
    }
  }

  // ---- exact kth value + survivor range [p0, G) ----
  const int kk = k > G ? G : k;
  const float kth = s_sval[G - kk];
  const float m = s_m;
  for (int i = tid; i < G; i += NT) {
    if (s_sval[i] >= kth && (i == 0 || s_sval[i - 1] < kth)) s_p0 = i;
  }
  __syncthreads();
  const int p0 = s_p0;

  // ---- softmax denom over survivors ----
  float part = 0.0f;
  for (int i = p0 + tid; i < G; i += NT) {
    float e = expf(s_sval[i] - m);
    s_e[i] = e;
    part += e;
  }
#pragma unroll
  for (int d = 32; d > 0; d >>= 1) part += __shfl_xor(part, d);
  if (lane == 0) s_wredf[wid] = part;
  __syncthreads();
  if (tid == 0) {
    float s = 0.0f;
    for (int i = 0; i < NWAVE; ++i) s += s_wredf[i];
    s_denom = s;
  }
  __syncthreads();
  const float denom = s_denom;

  // ---- sequential fp32 cumsum + top-p mask (batched loads, last kept) ----
  if (tid == 0) {
    const float cut = 1.0f - topp;
    float cs = 0.0f;
    int i = p0;
    for (; i + 8 <= G; i += 8) {
      float v0 = s_e[i], v1 = s_e[i + 1], v2 = s_e[i + 2], v3 = s_e[i + 3];
      float v4 = s_e[i + 4], v5 = s_e[i + 5], v6 = s_e[i + 6], v7 = s_e[i + 7];
      float d0 = v0 / denom, d1 = v1 / denom, d2 = v2 / denom, d3 = v3 / denom;
      float d4 = v4 / denom, d5 = v5 / denom, d6 = v6 / denom, d7 = v7 / denom;
      cs += d0; s_keep[i] = (cs <= cut) ? 0 : 1;
      cs += d1; s_keep[i + 1] = (cs <= cut) ? 0 : 1;
      cs += d2; s_keep[i + 2] = (cs <= cut) ? 0 : 1;
      cs += d3; s_keep[i + 3] = (cs <= cut) ? 0 : 1;
      cs += d4; s_keep[i + 4] = (cs <= cut) ? 0 : 1;
      cs += d5; s_keep[i + 5] = (cs <= cut) ? 0 : 1;
      cs += d6; s_keep[i + 6] = (cs <= cut) ? 0 : 1;
      cs += d7; s_keep[i + 7] = (cs <= cut) ? 0 : 1;
    }
    for (; i < G; ++i) {
      cs += s_e[i] / denom;
      s_keep[i] = (cs <= cut) ? 0 : 1;
    }
    s_keep[G - 1] = 1;
  }
  __syncthreads();

  // ---- final denom over kept ----
  part = 0.0f;
  for (int i = p0 + tid; i < G; i += NT)
    if (s_keep[i]) part += s_e[i];
#pragma unroll
  for (int d = 32; d > 0; d >>= 1) part += __shfl_xor(part, d);
  if (lane == 0) s_wredf[wid] = part;
  __syncthreads();
  if (tid == 0) {
    float s = 0.0f;
    for (int i = 0; i < NWAVE; ++i) s += s_wredf[i];
    s_denom2 = s;
  }
  __syncthreads();
  const float denom2 = s_denom2;

  // ---- overwrite s_e with final probs (0 for masked) ----
  for (int i = p0 + tid; i < G; i += NT)
    s_e[i] = s_keep[i] ? (s_e[i] / denom2) : 0.0f;
  __syncthreads();

  // ---- Gumbel scan over kept survivors (all in LDS) ----
  float bs = -INFINITY;
  int bi = 0x7FFFFFFF;
  for (int i = p0 + tid; i < G; i += NT) {
    if (!s_keep[i]) continue;
    int j = s_sidx[i];
    unsigned int t = (unsigned int)(row * V) + (unsigned int)j;
    unsigned int bb = tf_bits(t);
    float u = __uint_as_float((bb >> 9) | 0x3f800000u) - 1.0f;
    if (u < TINYF) u = TINYF;
    float g = -logf(-logf(u));
    float sc = s_sval[i] + g;
    if (sc > bs || (sc == bs && j < bi)) { bs = sc; bi = j; }
  }

  // ---- pass 3: write probs (chunk-max filtered; zeros without loads) ----
  const unsigned int kkey = fkey(kth);
  const int k16 = (int)(kkey >> 16);
  for (int q = tid; q < V4; q += NT) {
    vfloat4 o = (vfloat4){0.0f, 0.0f, 0.0f, 0.0f};
    if ((int)s_cmax16[q >> 2] >= k16) {
      float4 x4 = lg4[q];
      float raw[4] = {x4.x, x4.y, x4.z, x4.w};
      float os[4];
      const int j0 = q * 4;
      const int sh = j0 & 31;
      unsigned long long ww = (unsigned long long)s_seen[j0 >> 5] |
                              ((unsigned long long)s_seen[(j0 + 3) >> 5] << 32);
#pragma unroll
      for (int e = 0; e < 4; ++e) {
        float x = xform(raw[e], (ww >> (sh + e)) & 1ull, rp, irp, itemp);
        float pr = 0.0f;
        if (x >= kth) {
          int j = j0 + e;
          int lo = p0, hi = G;
          while (lo < hi) {
            int mid = (lo + hi) >> 1;
            float v = s_sval[mid];
            int id = s_sidx[mid];
            if (v < x || (v == x && id < j)) lo = mid + 1; else hi = mid;
          }
          pr = s_e[lo];
        }
        os[e] = pr;
      }
      o.x = os[0]; o.y = os[1]; o.z = os[2]; o.w = os[3];
    }
    __builtin_nontemporal_store(o, &pr4[q]);
  }

  // ---- argmax reduce -> sampled id ----
#pragma unroll
  for (int d = 32; d > 0; d >>= 1) {
    float ov = __shfl_down(bs, d);
    int oi = __shfl_down(bi, d);
    if (ov > bs || (ov == bs && oi < bi)) { bs = ov; bi = oi; }
  }
  if (lane == 0) { s_wredf[wid] = bs; s_wredi[wid] = bi; }
  __syncthreads();
  if (tid == 0) {
    float bb = s_wredf[0];
    int bj = s_wredi[0];
    for (int i = 1; i < NWAVE; ++i) {
      if (s_wredf[i] > bb || (s_wredf[i] == bb && s_wredi[i] < bj)) {
        bb = s_wredf[i];
        bj = s_wredi[i];
      }
    }
    out_ids[row] = (float)bj;
  }
}

extern "C" void kernel_launch(void* const* d_in, const int* in_sizes, int n_in,
                              void* d_out, int out_size, void* d_ws, size_t ws_size,
                              hipStream_t stream) {
  (void)in_sizes; (void)d_ws; (void)ws_size; (void)out_size;
  if (n_in < 6) return;
  const float* logits = (const float*)d_in[0];
  const int* toks = (const int*)d_in[1];
  const float* temps = (const float*)d_in[2];
  const float* topps = (const float*)d_in[3];
  const int* topks = (const int*)d_in[4];
  const float* rps = (const float*)d_in[5];
  float* out = (float*)d_out;            // [0,256): ids as float; [256,...): probs
  float* probs = out + NROWS;
  sampler_kernel<<<dim3(NROWS), dim3(NT), 0, stream>>>(
      logits, toks, temps, topps, topks, rps, out, probs);
}